// Round 3
// baseline (183.470 us; speedup 1.0000x reference)
//
#include <hip/hip_runtime.h>
#include <hip/hip_fp16.h>

typedef _Float16 f16x8 __attribute__((ext_vector_type(8)));
typedef float f32x4 __attribute__((ext_vector_type(4)));

union U4H8 { uint4 u; f16x8 h; };
__device__ inline f16x8 asH(uint4 u){ U4H8 x; x.u = u; return x.h; }
__device__ inline unsigned int pk(float a, float b){
    __half2 h = __floats2half2_rn(a, b);
    union { __half2 h; unsigned int u; } c; c.h = h; return c.u;
}
__device__ inline unsigned short h16(float a){
    union { __half h; unsigned short s; } c; c.h = __float2half(a); return c.s;
}

// ws dword layout: frags uint4[28][64] = dwords [0,7168);
// b1f f32[4][4][64] @7168; b2f f32[4][64] @8192; end 8448 dwords.
#define NFRAG 28
#define WS_B1 7168
#define WS_B2 8192

// frag fi: 0-1 conv1 (k=kh*8+kw); 2-14 conv2 (k=tap*16+ic, 13 MFMA);
//          15-26 fc1 (nt*6+kk, k=pos*12+oc2); 27 fc2 (k=fc1-col order)
__global__ __launch_bounds__(256) void build_tables(
    const float* __restrict__ H1w, const float* __restrict__ H1b,
    const float* __restrict__ H2w, const float* __restrict__ H2b,
    const float* __restrict__ H3w, const float* __restrict__ outw,
    unsigned int* __restrict__ ws)
{
    const int t = threadIdx.x, lane = t & 63, wv = t >> 6;
    const int ch = lane >> 4, oc = lane & 15;

    for (int fi = wv; fi < NFRAG; fi += 4) {
        unsigned short us[8];
        for (int j = 0; j < 8; ++j) {
            float w = 0.f;
            if (fi < 2) {                         // conv1
                int kh = fi * 4 + ch;
                if (kh < 5 && j < 5 && oc < 12) w = H1w[oc * 25 + kh * 5 + j];
            } else if (fi < 15) {                 // conv2 channels-last
                int kk = fi - 2;
                int tap = kk * 2 + (ch >> 1);
                int ic = (ch & 1) * 8 + j;
                if (tap < 25 && oc < 12) {
                    int kh = tap / 5, kw = tap % 5;
                    int q = oc >> 2, icl = -1;
                    if (q == 0)      { if (ic < 8) icl = ic; }
                    else if (q == 1) { if (ic >= 4 && ic < 12) icl = ic - 4; }
                    else             { if (ic < 4) icl = ic;
                                       else if (ic >= 8 && ic < 12) icl = ic - 4; }
                    if (icl >= 0) w = H2w[((oc * 8 + icl) * 5 + kh) * 5 + kw];
                }
            } else if (fi < 27) {                 // fc1 (k reordered to pos*12+oc2)
                int idx = fi - 15, nt = idx / 6, kk = idx % 6;
                int k = kk * 32 + ch * 8 + j;     // 0..191
                int pos = k / 12, oc2 = k % 12;
                int col = nt * 16 + oc;
                if (col < 30) w = H3w[(oc2 * 16 + pos) * 30 + col];
            } else {                              // fc2
                int k = ch * 8 + j;
                if (k < 30 && oc < 10) w = outw[k * 10 + oc];
            }
            us[j] = h16(w);
        }
        uint4 u;
        u.x = us[0] | ((unsigned int)us[1] << 16);
        u.y = us[2] | ((unsigned int)us[3] << 16);
        u.z = us[4] | ((unsigned int)us[5] << 16);
        u.w = us[6] | ((unsigned int)us[7] << 16);
        ((uint4*)ws)[fi * 64 + lane] = u;
    }

    float* wsf = (float*)ws;
    if (wv == 1) {            // conv1 bias with -1-pad contribution folded in
        for (int tt = 0; tt < 4; ++tt)
            for (int r = 0; r < 4; ++r) {
                int m = ch * 4 + r, oh = 2 * tt + (m >> 3), ow = m & 7;
                float v = 0.f;
                if (oc < 12) {
                    v = H1b[oc * 64 + oh * 8 + ow];
                    for (int kh = 0; kh < 5; ++kh)
                        for (int kw = 0; kw < 5; ++kw) {
                            int rr = 2 * oh + kh, cc = 2 * ow + kw;   // padded coords
                            if (rr < 2 || rr >= 18 || cc < 2 || cc >= 18)
                                v -= H1w[oc * 25 + kh * 5 + kw];
                        }
                }
                wsf[WS_B1 + (tt * 4 + r) * 64 + lane] = v;
            }
    }
    if (wv == 2) {            // conv2 bias with -1-pad folded
        for (int r = 0; r < 4; ++r) {
            int pos = ch * 4 + r, oh = pos >> 2, ow = pos & 3;
            float v = 0.f;
            if (oc < 12) {
                v = H2b[oc * 16 + oh * 4 + ow];
                for (int icl = 0; icl < 8; ++icl)
                    for (int kh = 0; kh < 5; ++kh)
                        for (int kw = 0; kw < 5; ++kw) {
                            int rr = 2 * oh + kh - 2, cc = 2 * ow + kw - 2;
                            if (rr < 0 || rr >= 8 || cc < 0 || cc >= 8)
                                v -= H2w[((oc * 8 + icl) * 5 + kh) * 5 + kw];
                        }
            }
            wsf[WS_B2 + r * 64 + lane] = v;
        }
    }
}

// ---------------- main kernel: barrier-free, 2 samples per wave ----------------
// per-wave LDS slice (12160 B stride):
//   xs  @0     : [2][20 rows][24 cols] half (zero guards)        1920 B
//   h1c @1920  : [2][144 pos][16 ch] half, XOR-swizzled          9216 B
//   h2  @11136 : [2][192] half, k = pos*12+oc                     768 B
//   h3  @11904 : [2][32] half                                     128 B
__global__ __launch_bounds__(256, 3) void modernnet_mfma(
    const float* __restrict__ x, const unsigned int* __restrict__ ws,
    const float* __restrict__ H3b, const float* __restrict__ outb,
    float* __restrict__ out)
{
    __shared__ unsigned int lds[12160];
    const int t = threadIdx.x, wave = t >> 6, l = t & 63;
    const int ch = l >> 4, m = l & 15;
    char* base = (char*)lds + wave * 12160;
    const int s0 = blockIdx.x * 8 + wave * 2;

    // preload fragments
    const uint4* fr = (const uint4*)ws;
    uint4 c1b0 = fr[0 * 64 + l], c1b1 = fr[1 * 64 + l];
    uint4 c2b[13];
    #pragma unroll
    for (int kk = 0; kk < 13; ++kk) c2b[kk] = fr[(2 + kk) * 64 + l];
    const float* wsf = (const float*)ws;
    f32x4 b1f[4];
    #pragma unroll
    for (int tt = 0; tt < 4; ++tt)
        #pragma unroll
        for (int r = 0; r < 4; ++r) b1f[tt][r] = wsf[WS_B1 + (tt * 4 + r) * 64 + l];
    f32x4 b2f;
    #pragma unroll
    for (int r = 0; r < 4; ++r) b2f[r] = wsf[WS_B2 + r * 64 + l];

    // per-lane conv2 read offsets within an h1c sample image
    int c2off[13];
    {
        const int mb = 24 * (m >> 2) + 2 * (m & 3);     // pos base for (oh,ow)
        const int hb = (ch & 1) << 4;
        #pragma unroll
        for (int kk = 0; kk < 13; ++kk) {
            int tap = kk * 2 + (ch >> 1); if (tap > 24) tap = 24;  // dead slot -> B=0
            int kh = tap / 5, kw = tap % 5;
            int pos = mb + kh * 12 + kw;
            c2off[kk] = ((pos << 5) + hb) ^ ((pos & 12) << 2);     // XOR swizzle
        }
    }

    // zero the whole slice (3008 dwords = 752 uint4)
    {
        uint4 z; z.x = z.y = z.z = z.w = 0u;
        #pragma unroll
        for (int i = 0; i < 12; ++i) {
            int idx = l + i * 64;
            if (idx < 752) ((uint4*)base)[idx] = z;
        }
    }

    // load x interior (2 samples x 16x16), convert to f16
    {
        const float* xp = x + (size_t)s0 * 256 + l * 8;
        float4 v0 = *(const float4*)xp;
        float4 v1 = *(const float4*)(xp + 4);
        int sI = l >> 5, idx = l & 31;
        int r = idx >> 1, c = (idx & 1) * 8;
        char* dst = base + sI * 960 + (r + 2) * 48 + (c + 2) * 2;
        ((unsigned int*)dst)[0] = pk(v0.x, v0.y);
        ((unsigned int*)dst)[1] = pk(v0.z, v0.w);
        ((unsigned int*)dst)[2] = pk(v1.x, v1.y);
        ((unsigned int*)dst)[3] = pk(v1.z, v1.w);
    }

    // conv1: per sample 4 M-tiles (2 oh-rows x 8 ow), 2 MFMA each
    #pragma unroll
    for (int s = 0; s < 2; ++s) {
        #pragma unroll
        for (int tt = 0; tt < 4; ++tt) {
            const char* ap = base + s * 960 + (2 * tt + (m >> 3)) * 96 + (m & 7) * 4;
            const unsigned int* p0 = (const unsigned int*)(ap + ch * 48);
            uint4 a0 = make_uint4(p0[0], p0[1], p0[2], p0[3]);
            const unsigned int* p1 = (const unsigned int*)(ap + 192);   // kh=4 row
            uint4 a1 = make_uint4(p1[0], p1[1], p1[2], p1[3]);
            f32x4 acc = b1f[tt];
            acc = __builtin_amdgcn_mfma_f32_16x16x32_f16(asH(a0), asH(c1b0), acc, 0, 0, 0);
            acc = __builtin_amdgcn_mfma_f32_16x16x32_f16(asH(a1), asH(c1b1), acc, 0, 0, 0);
            if (m < 12) {                       // C col = oc = m
                int p0i = (2 * tt + (ch >> 1) + 2) * 12 + (ch & 1) * 4 + 2;
                #pragma unroll
                for (int r = 0; r < 4; ++r) {
                    int pos = p0i + r;
                    int off = ((pos << 5) + m * 2) ^ ((pos & 12) << 2);
                    *(unsigned short*)(base + 1920 + s * 4608 + off) =
                        h16(fmaxf(acc[r], 0.f));
                }
            }
        }
    }

    // conv2: per sample 13 b128 reads + 13 MFMA
    #pragma unroll
    for (int s = 0; s < 2; ++s) {
        const char* hb1 = base + 1920 + s * 4608;
        f32x4 acc = b2f;
        #pragma unroll
        for (int kk = 0; kk < 13; ++kk) {
            uint4 a = *(const uint4*)(hb1 + c2off[kk]);
            acc = __builtin_amdgcn_mfma_f32_16x16x32_f16(asH(a), asH(c2b[kk]), acc, 0, 0, 0);
        }
        if (m < 12) {
            #pragma unroll
            for (int r = 0; r < 4; ++r) {
                int pos = ch * 4 + r;
                *(unsigned short*)(base + 11136 + s * 384 + pos * 24 + m * 2) =
                    h16(fmaxf(acc[r], 0.f));
            }
        }
    }

    // fc1: 2 N-tiles x 6 MFMA (M rows 0,1 = our samples)
    #pragma unroll
    for (int nt = 0; nt < 2; ++nt) {
        int col = nt * 16 + m;
        float bias = (col < 30) ? H3b[col] : 0.f;
        f32x4 acc = { bias, bias, bias, bias };
        #pragma unroll
        for (int kk = 0; kk < 6; ++kk) {
            uint4 b = fr[(15 + nt * 6 + kk) * 64 + l];
            uint4 a = *(const uint4*)(base + 11136 + (m & 1) * 384 + kk * 64 + ch * 16);
            acc = __builtin_amdgcn_mfma_f32_16x16x32_f16(asH(a), asH(b), acc, 0, 0, 0);
        }
        if (ch == 0 && col < 30) {
            *(unsigned short*)(base + 11904 + 0 * 64 + col * 2) = h16(fmaxf(acc[0], 0.f));
            *(unsigned short*)(base + 11904 + 1 * 64 + col * 2) = h16(fmaxf(acc[1], 0.f));
        }
    }

    // fc2: 1 MFMA
    {
        uint4 b = fr[27 * 64 + l];
        float bias = (m < 10) ? outb[m] : 0.f;
        f32x4 acc = { bias, bias, bias, bias };
        uint4 a = *(const uint4*)(base + 11904 + (m & 1) * 64 + ch * 16);
        acc = __builtin_amdgcn_mfma_f32_16x16x32_f16(asH(a), asH(b), acc, 0, 0, 0);
        if (ch == 0 && m < 10) {
            out[(size_t)s0 * 10 + m]       = acc[0];
            out[(size_t)(s0 + 1) * 10 + m] = acc[1];
        }
    }
}

extern "C" void kernel_launch(void* const* d_in, const int* in_sizes, int n_in,
                              void* d_out, int out_size, void* d_ws, size_t ws_size,
                              hipStream_t stream) {
    const float* x    = (const float*)d_in[0];
    const float* H1w  = (const float*)d_in[1];
    const float* H1b  = (const float*)d_in[2];
    const float* H2w  = (const float*)d_in[3];
    const float* H2b  = (const float*)d_in[4];
    const float* H3w  = (const float*)d_in[5];
    const float* H3b  = (const float*)d_in[6];
    const float* outw = (const float*)d_in[7];
    const float* outb = (const float*)d_in[8];
    float* outp = (float*)d_out;
    unsigned int* ws = (unsigned int*)d_ws;

    build_tables<<<1, 256, 0, stream>>>(H1w, H1b, H2w, H2b, H3w, outw, ws);

    const int B = in_sizes[0] / 256;          // 131072
    const int blocks = B / 8;                 // 16384
    modernnet_mfma<<<blocks, 256, 0, stream>>>(x, ws, H3b, outb, outp);
}

// Round 4
// 111.029 us; speedup vs baseline: 1.6525x; 1.6525x over previous
//
#include <hip/hip_runtime.h>
#include <hip/hip_fp16.h>

typedef _Float16 f16x8 __attribute__((ext_vector_type(8)));
typedef float f32x4 __attribute__((ext_vector_type(4)));

union U4H8 { uint4 u; f16x8 h; };
__device__ inline f16x8 asH(uint4 u){ U4H8 x; x.u = u; return x.h; }
__device__ inline unsigned int pk(float a, float b){
    __half2 h = __floats2half2_rn(a, b);
    union { __half2 h; unsigned int u; } c; c.h = h; return c.u;
}
__device__ inline unsigned short h16(float a){
    union { __half h; unsigned short s; } c; c.h = __float2half(a); return c.s;
}

// ws dword layout: frags uint4[28][64] = dwords [0,7168);
// b1f f32[16][64] @7168 (transposed C: oc=4ch+r, col=pos); b2f f32[4][64] @8192.
#define NFRAG 28
#define WS_B1 7168
#define WS_B2 8192

// frag fi: 0-1 conv1 (k=kh*8+kw, rows=oc); 2-14 conv2 (k=tap*16+ic, rows=oc);
//          15-26 fc1 (nt*6+kk, k=pos*12+oc2, rows=fc-col); 27 fc2
__global__ __launch_bounds__(256) void build_tables(
    const float* __restrict__ H1w, const float* __restrict__ H1b,
    const float* __restrict__ H2w, const float* __restrict__ H2b,
    const float* __restrict__ H3w, const float* __restrict__ outw,
    unsigned int* __restrict__ ws)
{
    const int t = threadIdx.x, b = blockIdx.x;
    float* wsf = (float*)ws;

    if (b < NFRAG) {
        if (t < 64) {
            const int lane = t, ch = lane >> 4, oc = lane & 15;
            const int fi = b;
            unsigned short us[8];
            for (int j = 0; j < 8; ++j) {
                float w = 0.f;
                if (fi < 2) {                         // conv1
                    int kh = fi * 4 + ch;
                    if (kh < 5 && j < 5 && oc < 12) w = H1w[oc * 25 + kh * 5 + j];
                } else if (fi < 15) {                 // conv2 channels-last
                    int kk = fi - 2;
                    int tap = kk * 2 + (ch >> 1);
                    int ic = (ch & 1) * 8 + j;
                    if (tap < 25 && oc < 12) {
                        int kh = tap / 5, kw = tap % 5;
                        int q = oc >> 2, icl = -1;
                        if (q == 0)      { if (ic < 8) icl = ic; }
                        else if (q == 1) { if (ic >= 4 && ic < 12) icl = ic - 4; }
                        else             { if (ic < 4) icl = ic;
                                           else if (ic >= 8 && ic < 12) icl = ic - 4; }
                        if (icl >= 0) w = H2w[((oc * 8 + icl) * 5 + kh) * 5 + kw];
                    }
                } else if (fi < 27) {                 // fc1 (k = pos*12+oc2)
                    int idx = fi - 15, nt = idx / 6, kk = idx % 6;
                    int k = kk * 32 + ch * 8 + j;     // 0..191
                    int pos = k / 12, oc2 = k % 12;
                    int col = nt * 16 + oc;
                    if (col < 30) w = H3w[(oc2 * 16 + pos) * 30 + col];
                } else {                              // fc2
                    int k = ch * 8 + j;
                    if (k < 30 && oc < 10) w = outw[k * 10 + oc];
                }
                us[j] = h16(w);
            }
            uint4 u;
            u.x = us[0] | ((unsigned int)us[1] << 16);
            u.y = us[2] | ((unsigned int)us[3] << 16);
            u.z = us[4] | ((unsigned int)us[5] << 16);
            u.w = us[6] | ((unsigned int)us[7] << 16);
            ((uint4*)ws)[fi * 64 + lane] = u;
        }
    } else if (b == NFRAG) {        // b1f transposed: entry e=tt*4+r, lane(ch,m)
        for (int idx = t; idx < 1024; idx += 256) {
            int e = idx >> 6, l2 = idx & 63;
            int tt = e >> 2, r = e & 3;
            int oc = 4 * (l2 >> 4) + r, m2 = l2 & 15;
            int oh = 2 * tt + (m2 >> 3), ow = m2 & 7;
            float v = 0.f;
            if (oc < 12) {
                v = H1b[oc * 64 + oh * 8 + ow];
                for (int kh = 0; kh < 5; ++kh)
                    for (int kw = 0; kw < 5; ++kw) {
                        int rr = 2 * oh + kh, cc = 2 * ow + kw;
                        if (rr < 2 || rr >= 18 || cc < 2 || cc >= 18)
                            v -= H1w[oc * 25 + kh * 5 + kw];
                    }
            }
            wsf[WS_B1 + e * 64 + l2] = v;
        }
    } else {                        // b2f transposed: entry r, lane(ch,m)
        int e = t >> 6, l2 = t & 63;
        int oc = 4 * (l2 >> 4) + e, m2 = l2 & 15;
        int oh = m2 >> 2, ow = m2 & 3;
        float v = 0.f;
        if (oc < 12) {
            v = H2b[oc * 16 + oh * 4 + ow];
            for (int icl = 0; icl < 8; ++icl)
                for (int kh = 0; kh < 5; ++kh)
                    for (int kw = 0; kw < 5; ++kw) {
                        int rr = 2 * oh + kh - 2, cc = 2 * ow + kw - 2;
                        if (rr < 0 || rr >= 8 || cc < 0 || cc >= 8)
                            v -= H2w[((oc * 8 + icl) * 5 + kh) * 5 + kw];
                    }
        }
        wsf[WS_B2 + e * 64 + l2] = v;
    }
}

// ---------------- main kernel: barrier-free, 2 samples/wave, xs overlaid ----
// per-wave slice (10112 B):
//   h1c_s @ s*4608 : [144 pos][16 ch] half, XOR-swizzled      2 x 4608 B
//   (xs overlay @ 0..1919 : [2][20 rows][24 cols] half — dead after conv1 reads)
//   h2 @ 9216 (+s*384) : [16 pos][12 oc] half                  768 B
//   h3 @ 9984 (+s*64)  : [32] half                             128 B
#define SLICE 10112
__global__ __launch_bounds__(256, 4) void modernnet_mfma(
    const float* __restrict__ x, const unsigned int* __restrict__ ws,
    const float* __restrict__ H3b, const float* __restrict__ outb,
    float* __restrict__ out)
{
    __shared__ uint4 lds4[4 * SLICE / 16];
    const int t = threadIdx.x, wave = t >> 6, l = t & 63;
    const int ch = l >> 4, m = l & 15;
    char* base = (char*)lds4 + wave * SLICE;
    const int s0 = blockIdx.x * 8 + wave * 2;

    const uint4* fr = (const uint4*)ws;
    const float* wsf = (const float*)ws;

    // conv1 weights + bias C-frags
    uint4 c1b0 = fr[0 * 64 + l], c1b1 = fr[1 * 64 + l];
    f32x4 b1f[4];
    #pragma unroll
    for (int tt = 0; tt < 4; ++tt)
        #pragma unroll
        for (int r = 0; r < 4; ++r) b1f[tt][r] = wsf[WS_B1 + (tt * 4 + r) * 64 + l];

    // conv2 per-lane read offsets (col = pos = m)
    int c2off[13];
    {
        const int mb = 24 * (m >> 2) + 2 * (m & 3);
        const int hb = (ch & 1) << 4;
        #pragma unroll
        for (int kk = 0; kk < 13; ++kk) {
            int tap = kk * 2 + (ch >> 1); if (tap > 24) tap = 24;
            int kh = tap / 5, kw = tap % 5;
            int pos = mb + kh * 12 + kw;
            c2off[kk] = ((pos << 5) + hb) ^ ((pos & 12) << 2);
        }
    }

    // zero xs region (1920 B = 120 uint4)
    {
        uint4 z; z.x = z.y = z.z = z.w = 0u;
        ((uint4*)base)[l] = z;
        if (l < 56) ((uint4*)base)[64 + l] = z;
    }

    // load x interior (2 samples x 16x16) -> f16
    {
        const float* xp = x + (size_t)s0 * 256 + l * 8;
        float4 v0 = *(const float4*)xp;
        float4 v1 = *(const float4*)(xp + 4);
        int sI = l >> 5, idx = l & 31;
        int r = idx >> 1, c = (idx & 1) * 8;
        char* dst = base + sI * 960 + (r + 2) * 48 + (c + 2) * 2;
        ((unsigned int*)dst)[0] = pk(v0.x, v0.y);
        ((unsigned int*)dst)[1] = pk(v0.z, v0.w);
        ((unsigned int*)dst)[2] = pk(v1.x, v1.y);
        ((unsigned int*)dst)[3] = pk(v1.z, v1.w);
    }

    // conv1 MFMAs: all reads before any h1c write (xs is overlaid)
    f32x4 acc1[8];
    #pragma unroll
    for (int i = 0; i < 8; ++i) {
        const int s = i >> 2, tt = i & 3;
        const char* ap = base + s * 960 + (2 * tt + (m >> 3)) * 96 + (m & 7) * 4;
        const unsigned int* p0 = (const unsigned int*)(ap + ch * 48);
        uint4 b0 = make_uint4(p0[0], p0[1], p0[2], p0[3]);
        uint4 b1 = make_uint4(0u, 0u, 0u, 0u);
        if (ch == 0) {
            const unsigned int* p1 = (const unsigned int*)(ap + 192);
            b1 = make_uint4(p1[0], p1[1], p1[2], p1[3]);
        }
        f32x4 acc = b1f[tt];
        acc = __builtin_amdgcn_mfma_f32_16x16x32_f16(asH(c1b0), asH(b0), acc, 0, 0, 0);
        acc = __builtin_amdgcn_mfma_f32_16x16x32_f16(asH(c1b1), asH(b1), acc, 0, 0, 0);
        acc1[i] = acc;
    }

    // conv1 epilogue: rows=oc (regs), col=pos -> one b64 write per tile
    #pragma unroll
    for (int i = 0; i < 8; ++i) {
        const int s = i >> 2, tt = i & 3;
        const int pos = (2 * tt + (m >> 3) + 2) * 12 + (m & 7) + 2;
        const int off = ((pos << 5) + ch * 8) ^ ((pos & 12) << 2);
        unsigned int w0 = pk(fmaxf(acc1[i][0], 0.f), fmaxf(acc1[i][1], 0.f));
        unsigned int w1 = pk(fmaxf(acc1[i][2], 0.f), fmaxf(acc1[i][3], 0.f));
        *(uint2*)(base + s * 4608 + off) = make_uint2(w0, w1);
    }

    // prefetch conv2 weights + bias (latency hidden under ring-zero)
    uint4 c2b[13];
    #pragma unroll
    for (int kk = 0; kk < 13; ++kk) c2b[kk] = fr[(2 + kk) * 64 + l];
    f32x4 b2f;
    #pragma unroll
    for (int r = 0; r < 4; ++r) b2f[r] = wsf[WS_B2 + r * 64 + l];

    // zero h1c pad rings (2 samples x 80 pos x 32 B = 320 16B-chunks)
    {
        uint4 z; z.x = z.y = z.z = z.w = 0u;
        #pragma unroll
        for (int k2 = 0; k2 < 5; ++k2) {
            int idx = l + k2 * 64;              // 0..319
            int smp = (idx >= 160) ? 1 : 0;
            int ci = idx - smp * 160;
            int pi = ci >> 1, half = ci & 1;
            int pos;
            if (pi < 24) pos = pi;
            else if (pi < 48) pos = pi + 96;
            else {
                int q = pi - 48;
                int c = q & 3; c = (c < 2) ? c : c + 8;
                pos = (2 + (q >> 2)) * 12 + c;
            }
            int off = ((pos << 5) + (half << 4)) ^ ((pos & 12) << 2);
            *(uint4*)(base + smp * 4608 + off) = z;
        }
    }

    // conv2: 13 b128 reads + 13 MFMA per sample; epilogue b64 to h2[pos][12oc]
    #pragma unroll
    for (int s = 0; s < 2; ++s) {
        const char* hb1 = base + s * 4608;
        f32x4 acc = b2f;
        #pragma unroll
        for (int kk = 0; kk < 13; ++kk) {
            uint4 a = *(const uint4*)(hb1 + c2off[kk]);
            acc = __builtin_amdgcn_mfma_f32_16x16x32_f16(asH(c2b[kk]), asH(a), acc, 0, 0, 0);
        }
        if (ch < 3) {
            unsigned int w0 = pk(fmaxf(acc[0], 0.f), fmaxf(acc[1], 0.f));
            unsigned int w1 = pk(fmaxf(acc[2], 0.f), fmaxf(acc[3], 0.f));
            *(uint2*)(base + 9216 + s * 384 + m * 24 + ch * 8) = make_uint2(w0, w1);
        }
    }

    // fc1: rows = fc-col j (regs), col = sample
    #pragma unroll
    for (int nt = 0; nt < 2; ++nt) {
        const int jb = nt * 16 + 4 * ch;
        f32x4 acc;
        #pragma unroll
        for (int r = 0; r < 4; ++r) acc[r] = (jb + r < 30) ? H3b[jb + r] : 0.f;
        #pragma unroll
        for (int kk = 0; kk < 6; ++kk) {
            uint4 bw = fr[(15 + nt * 6 + kk) * 64 + l];
            uint4 aa = *(const uint4*)(base + 9216 + (m & 1) * 384 + kk * 64 + ch * 16);
            acc = __builtin_amdgcn_mfma_f32_16x16x32_f16(asH(bw), asH(aa), acc, 0, 0, 0);
        }
        if (m < 2) {
            unsigned int w0 = pk(fmaxf(acc[0], 0.f), fmaxf(acc[1], 0.f));
            unsigned int w1 = pk(fmaxf(acc[2], 0.f), fmaxf(acc[3], 0.f));
            *(uint2*)(base + 9984 + m * 64 + nt * 32 + ch * 8) = make_uint2(w0, w1);
        }
    }

    // fc2: rows = logit j, col = sample
    {
        uint4 bw = fr[27 * 64 + l];
        uint4 aa = *(const uint4*)(base + 9984 + (m & 1) * 64 + ch * 16);
        f32x4 acc;
        #pragma unroll
        for (int r = 0; r < 4; ++r) acc[r] = (4 * ch + r < 10) ? outb[4 * ch + r] : 0.f;
        acc = __builtin_amdgcn_mfma_f32_16x16x32_f16(asH(bw), asH(aa), acc, 0, 0, 0);
        if (m < 2) {
            float* op = out + (size_t)(s0 + m) * 10 + 4 * ch;
            if (ch < 2) {
                *(float2*)op       = make_float2(acc[0], acc[1]);
                *(float2*)(op + 2) = make_float2(acc[2], acc[3]);
            } else if (ch == 2) {
                *(float2*)op       = make_float2(acc[0], acc[1]);
            }
        }
    }
}

extern "C" void kernel_launch(void* const* d_in, const int* in_sizes, int n_in,
                              void* d_out, int out_size, void* d_ws, size_t ws_size,
                              hipStream_t stream) {
    const float* x    = (const float*)d_in[0];
    const float* H1w  = (const float*)d_in[1];
    const float* H1b  = (const float*)d_in[2];
    const float* H2w  = (const float*)d_in[3];
    const float* H2b  = (const float*)d_in[4];
    const float* H3w  = (const float*)d_in[5];
    const float* H3b  = (const float*)d_in[6];
    const float* outw = (const float*)d_in[7];
    const float* outb = (const float*)d_in[8];
    float* outp = (float*)d_out;
    unsigned int* ws = (unsigned int*)d_ws;

    build_tables<<<30, 256, 0, stream>>>(H1w, H1b, H2w, H2b, H3w, outw, ws);

    const int B = in_sizes[0] / 256;          // 131072
    const int blocks = B / 8;                 // 16384
    modernnet_mfma<<<blocks, 256, 0, stream>>>(x, ws, H3b, outb, outp);
}

// Round 5
// 92.641 us; speedup vs baseline: 1.9805x; 1.1985x over previous
//
#include <hip/hip_runtime.h>
#include <hip/hip_fp16.h>

typedef _Float16 f16x8 __attribute__((ext_vector_type(8)));
typedef float f32x4 __attribute__((ext_vector_type(4)));

union U4H8 { uint4 u; f16x8 h; };
__device__ inline f16x8 asH(uint4 u){ U4H8 x; x.u = u; return x.h; }
__device__ inline unsigned int pk(float a, float b){
    __half2 h = __floats2half2_rn(a, b);
    union { __half2 h; unsigned int u; } c; c.h = h; return c.u;
}
__device__ inline unsigned short h16(float a){
    union { __half h; unsigned short s; } c; c.h = __float2half(a); return c.s;
}

// ws dword layout: frags uint4[28][64] = dwords [0,7168);
// b1f f32[16][64] @7168 | b2f f32[4][64] @8192 | b3f f32[8][64] @8448 |
// b4f f32[4][64] @8960 ; end 9216 dwords (36 KiB).
#define NFRAG 28
#define WS_B1 7168
#define WS_B2 8192
#define WS_B3 8448
#define WS_B4 8960

// frag fi: 0-1 conv1 (k=kh*8+kw, rows=oc); 2-14 conv2 (k=tap*16+ic, rows=oc);
//          15-26 fc1 (nt*6+kk, k=pos*12+oc2, rows=fc-col); 27 fc2 (rows=logit)
__global__ __launch_bounds__(256) void build_tables(
    const float* __restrict__ H1w, const float* __restrict__ H1b,
    const float* __restrict__ H2w, const float* __restrict__ H2b,
    const float* __restrict__ H3w, const float* __restrict__ H3b,
    const float* __restrict__ outw, const float* __restrict__ outb,
    unsigned int* __restrict__ ws)
{
    const int t = threadIdx.x, b = blockIdx.x;
    float* wsf = (float*)ws;

    if (b < NFRAG) {
        if (t < 64) {
            const int lane = t, ch = lane >> 4, oc = lane & 15;
            const int fi = b;
            unsigned short us[8];
            for (int j = 0; j < 8; ++j) {
                float w = 0.f;
                if (fi < 2) {                         // conv1
                    int kh = fi * 4 + ch;
                    if (kh < 5 && j < 5 && oc < 12) w = H1w[oc * 25 + kh * 5 + j];
                } else if (fi < 15) {                 // conv2 channels-last
                    int kk = fi - 2;
                    int tap = kk * 2 + (ch >> 1);
                    int ic = (ch & 1) * 8 + j;
                    if (tap < 25 && oc < 12) {
                        int kh = tap / 5, kw = tap % 5;
                        int q = oc >> 2, icl = -1;
                        if (q == 0)      { if (ic < 8) icl = ic; }
                        else if (q == 1) { if (ic >= 4 && ic < 12) icl = ic - 4; }
                        else             { if (ic < 4) icl = ic;
                                           else if (ic >= 8 && ic < 12) icl = ic - 4; }
                        if (icl >= 0) w = H2w[((oc * 8 + icl) * 5 + kh) * 5 + kw];
                    }
                } else if (fi < 27) {                 // fc1 (k = pos*12+oc2)
                    int idx = fi - 15, nt = idx / 6, kk = idx % 6;
                    int k = kk * 32 + ch * 8 + j;     // 0..191
                    int pos = k / 12, oc2 = k % 12;
                    int col = nt * 16 + oc;
                    if (col < 30) w = H3w[(oc2 * 16 + pos) * 30 + col];
                } else {                              // fc2
                    int k = ch * 8 + j;
                    if (k < 30 && oc < 10) w = outw[k * 10 + oc];
                }
                us[j] = h16(w);
            }
            uint4 u;
            u.x = us[0] | ((unsigned int)us[1] << 16);
            u.y = us[2] | ((unsigned int)us[3] << 16);
            u.z = us[4] | ((unsigned int)us[5] << 16);
            u.w = us[6] | ((unsigned int)us[7] << 16);
            ((uint4*)ws)[fi * 64 + lane] = u;
        }
    } else if (b == NFRAG) {        // b1f: entry e=tt*4+r, lane(ch,m); oc=4ch+r
        for (int idx = t; idx < 1024; idx += 256) {
            int e = idx >> 6, l2 = idx & 63;
            int tt = e >> 2, r = e & 3;
            int oc = 4 * (l2 >> 4) + r, m2 = l2 & 15;
            int oh = 2 * tt + (m2 >> 3), ow = m2 & 7;
            float v = 0.f;
            if (oc < 12) {
                v = H1b[oc * 64 + oh * 8 + ow];
                for (int kh = 0; kh < 5; ++kh)
                    for (int kw = 0; kw < 5; ++kw) {
                        int rr = 2 * oh + kh, cc = 2 * ow + kw;
                        if (rr < 2 || rr >= 18 || cc < 2 || cc >= 18)
                            v -= H1w[oc * 25 + kh * 5 + kw];
                    }
            }
            wsf[WS_B1 + e * 64 + l2] = v;
        }
    } else {                        // b2f + b3f + b4f
        {
            int e = t >> 6, l2 = t & 63;
            int oc = 4 * (l2 >> 4) + e, m2 = l2 & 15;
            int oh = m2 >> 2, ow = m2 & 3;
            float v = 0.f;
            if (oc < 12) {
                v = H2b[oc * 16 + oh * 4 + ow];
                for (int icl = 0; icl < 8; ++icl)
                    for (int kh = 0; kh < 5; ++kh)
                        for (int kw = 0; kw < 5; ++kw) {
                            int rr = 2 * oh + kh - 2, cc = 2 * ow + kw - 2;
                            if (rr < 0 || rr >= 8 || cc < 0 || cc >= 8)
                                v -= H2w[((oc * 8 + icl) * 5 + kh) * 5 + kw];
                        }
            }
            wsf[WS_B2 + e * 64 + l2] = v;
        }
        for (int i = t; i < 512; i += 256) {    // b3f: e = nt*4+r
            int e = i >> 6, l2 = i & 63;
            int nt = e >> 2, r = e & 3, ch = l2 >> 4;
            int j = nt * 16 + 4 * ch + r;
            wsf[WS_B3 + e * 64 + l2] = (j < 30) ? H3b[j] : 0.f;
        }
        {                                        // b4f: e = r
            int e = t >> 6, l2 = t & 63, ch = l2 >> 4;
            int j = 4 * ch + e;
            wsf[WS_B4 + e * 64 + l2] = (j < 10) ? outb[j] : 0.f;
        }
    }
}

// ---------------- main kernel ----------------
// Block LDS (40576 B):
//   per-wave h1c @ wave*9216 : 2 samples x [144 pos][16 ch] half, XOR-swizzled
//     (xs overlay @ wave*9216 + s*960 : [20 rows][24 cols] half, dead after conv1)
//   shared h2 @ 36864 : 8 slots x 400 B ([16 pos][12 oc] half, padded)
//   shared h3 @ 40064 : 8 slots x 64 B ([32 j] half)
#define H2B 36864
#define H3B 40064
__global__ __launch_bounds__(256, 4) void modernnet_mfma(
    const float* __restrict__ x, const unsigned int* __restrict__ ws,
    float* __restrict__ out)
{
    __shared__ uint4 lds4[2536];
    char* L = (char*)lds4;
    const int t = threadIdx.x, wave = t >> 6, l = t & 63;
    const int ch = l >> 4, m = l & 15;
    char* base = L + wave * 9216;
    const int sblk = blockIdx.x * 8;
    const int s0 = sblk + wave * 2;

    const uint4* fr = (const uint4*)ws;
    const float* wsf = (const float*)ws;

    // conv1 weight + bias frags
    uint4 c1b0 = fr[0 * 64 + l], c1b1 = fr[1 * 64 + l];
    f32x4 b1f[4];
    #pragma unroll
    for (int tt = 0; tt < 4; ++tt)
        #pragma unroll
        for (int r = 0; r < 4; ++r) b1f[tt][r] = wsf[WS_B1 + (tt * 4 + r) * 64 + l];

    // conv2 per-lane read offsets — all-constant fold, no divides
    int c2off[13];
    {
        const int mb = 24 * (m >> 2) + 2 * (m & 3);
        const int hb = (ch & 1) << 4;
        const int sel = (ch >> 1) & 1;
        #pragma unroll
        for (int kk = 0; kk < 13; ++kk) {
            const int t0 = 2 * kk;
            const int t1 = (2 * kk + 1 <= 24) ? 2 * kk + 1 : 24;
            const int p0 = (t0 / 5) * 12 + (t0 % 5);
            const int p1 = (t1 / 5) * 12 + (t1 % 5);
            int pos = mb + (sel ? p1 : p0);
            c2off[kk] = ((pos << 5) + hb) ^ ((pos & 12) << 2);
        }
    }

    // zero xs region (1920 B)
    {
        uint4 z; z.x = z.y = z.z = z.w = 0u;
        ((uint4*)base)[l] = z;
        if (l < 56) ((uint4*)base)[64 + l] = z;
    }

    // load x interior (2 samples x 16x16) -> f16
    {
        const float* xp = x + (size_t)s0 * 256 + l * 8;
        float4 v0 = *(const float4*)xp;
        float4 v1 = *(const float4*)(xp + 4);
        int sI = l >> 5, idx = l & 31;
        int r = idx >> 1, c = (idx & 1) * 8;
        char* dst = base + sI * 960 + (r + 2) * 48 + (c + 2) * 2;
        ((unsigned int*)dst)[0] = pk(v0.x, v0.y);
        ((unsigned int*)dst)[1] = pk(v0.z, v0.w);
        ((unsigned int*)dst)[2] = pk(v1.x, v1.y);
        ((unsigned int*)dst)[3] = pk(v1.z, v1.w);
    }

    // conv1 MFMAs (reads complete before h1c writes; xs overlaid)
    f32x4 acc1[8];
    #pragma unroll
    for (int i = 0; i < 8; ++i) {
        const int s = i >> 2, tt = i & 3;
        const char* ap = base + s * 960 + (2 * tt + (m >> 3)) * 96 + (m & 7) * 4;
        const unsigned int* p0 = (const unsigned int*)(ap + ch * 48);
        uint4 b0 = make_uint4(p0[0], p0[1], p0[2], p0[3]);
        const unsigned int* p1 = (const unsigned int*)(ap + 192);   // kh=4 row
        uint4 b1 = make_uint4(p1[0], p1[1], p1[2], p1[3]);          // junk for ch>0: A=0
        f32x4 acc = b1f[tt];
        acc = __builtin_amdgcn_mfma_f32_16x16x32_f16(asH(c1b0), asH(b0), acc, 0, 0, 0);
        acc = __builtin_amdgcn_mfma_f32_16x16x32_f16(asH(c1b1), asH(b1), acc, 0, 0, 0);
        acc1[i] = acc;
    }

    // conv1 epilogue: rows=oc in regs, col=pos -> b64 writes
    #pragma unroll
    for (int i = 0; i < 8; ++i) {
        const int s = i >> 2, tt = i & 3;
        const int pos = (2 * tt + (m >> 3) + 2) * 12 + (m & 7) + 2;
        const int off = ((pos << 5) + ch * 8) ^ ((pos & 12) << 2);
        unsigned int w0 = pk(fmaxf(acc1[i][0], 0.f), fmaxf(acc1[i][1], 0.f));
        unsigned int w1 = pk(fmaxf(acc1[i][2], 0.f), fmaxf(acc1[i][3], 0.f));
        *(uint2*)(base + s * 4608 + off) = make_uint2(w0, w1);
    }

    // prefetch conv2 weights + bias
    uint4 c2b[13];
    #pragma unroll
    for (int kk = 0; kk < 13; ++kk) c2b[kk] = fr[(2 + kk) * 64 + l];
    f32x4 b2f;
    #pragma unroll
    for (int r = 0; r < 4; ++r) b2f[r] = wsf[WS_B2 + r * 64 + l];

    // zero h1c pad rings
    {
        uint4 z; z.x = z.y = z.z = z.w = 0u;
        #pragma unroll
        for (int k2 = 0; k2 < 5; ++k2) {
            int idx = l + k2 * 64;
            int smp = (idx >= 160) ? 1 : 0;
            int ci = idx - smp * 160;
            int pi = ci >> 1, half = ci & 1;
            int pos;
            if (pi < 24) pos = pi;
            else if (pi < 48) pos = pi + 96;
            else {
                int q = pi - 48;
                int c = q & 3; c = (c < 2) ? c : c + 8;
                pos = (2 + (q >> 2)) * 12 + c;
            }
            int off = ((pos << 5) + (half << 4)) ^ ((pos & 12) << 2);
            *(uint4*)(base + smp * 4608 + off) = z;
        }
    }

    // conv2: two independent acc chains interleaved for ILP
    {
        const char* h0 = base;
        const char* h1 = base + 4608;
        f32x4 a0 = b2f, a1 = b2f;
        #pragma unroll
        for (int kk = 0; kk < 13; ++kk) {
            uint4 r0 = *(const uint4*)(h0 + c2off[kk]);
            uint4 r1 = *(const uint4*)(h1 + c2off[kk]);
            a0 = __builtin_amdgcn_mfma_f32_16x16x32_f16(asH(c2b[kk]), asH(r0), a0, 0, 0, 0);
            a1 = __builtin_amdgcn_mfma_f32_16x16x32_f16(asH(c2b[kk]), asH(r1), a1, 0, 0, 0);
        }
        if (ch < 3) {
            unsigned int w0 = pk(fmaxf(a0[0], 0.f), fmaxf(a0[1], 0.f));
            unsigned int w1 = pk(fmaxf(a0[2], 0.f), fmaxf(a0[3], 0.f));
            *(uint2*)(L + H2B + (wave * 2 + 0) * 400 + m * 24 + ch * 8) = make_uint2(w0, w1);
            w0 = pk(fmaxf(a1[0], 0.f), fmaxf(a1[1], 0.f));
            w1 = pk(fmaxf(a1[2], 0.f), fmaxf(a1[3], 0.f));
            *(uint2*)(L + H2B + (wave * 2 + 1) * 400 + m * 24 + ch * 8) = make_uint2(w0, w1);
        }
    }

    // prefetch fc1 frags (waves 0,1 only; nt = wave)
    uint4 afc[6];
    if (wave < 2) {
        #pragma unroll
        for (int kk = 0; kk < 6; ++kk) afc[kk] = fr[(15 + wave * 6 + kk) * 64 + l];
    }

    __syncthreads();

    // fc1: block-cooperative, M-rows = fc cols (regs), N-cols = 8 samples
    if (wave < 2) {
        const int nt = wave;
        f32x4 acc;
        #pragma unroll
        for (int r = 0; r < 4; ++r) acc[r] = wsf[WS_B3 + (nt * 4 + r) * 64 + l];
        #pragma unroll
        for (int kk = 0; kk < 6; ++kk) {
            uint4 bb = *(const uint4*)(L + H2B + (m & 7) * 400 + kk * 64 + ch * 16);
            acc = __builtin_amdgcn_mfma_f32_16x16x32_f16(asH(afc[kk]), asH(bb), acc, 0, 0, 0);
        }
        if (m < 8) {
            unsigned int w0 = pk(fmaxf(acc[0], 0.f), fmaxf(acc[1], 0.f));
            unsigned int w1 = pk(fmaxf(acc[2], 0.f), fmaxf(acc[3], 0.f));
            *(uint2*)(L + H3B + m * 64 + nt * 32 + ch * 8) = make_uint2(w0, w1);
        }
    }

    __syncthreads();

    // fc2: wave 0 only, 1 MFMA for all 8 samples
    if (wave == 0) {
        uint4 aw = fr[27 * 64 + l];
        uint4 bb = *(const uint4*)(L + H3B + (m & 7) * 64 + ch * 16);
        f32x4 acc;
        #pragma unroll
        for (int r = 0; r < 4; ++r) acc[r] = wsf[WS_B4 + r * 64 + l];
        acc = __builtin_amdgcn_mfma_f32_16x16x32_f16(asH(aw), asH(bb), acc, 0, 0, 0);
        if (m < 8) {
            float* op = out + (size_t)(sblk + m) * 10 + 4 * ch;
            if (ch < 2) {
                *(float2*)op       = make_float2(acc[0], acc[1]);
                *(float2*)(op + 2) = make_float2(acc[2], acc[3]);
            } else if (ch == 2) {
                *(float2*)op       = make_float2(acc[0], acc[1]);
            }
        }
    }
}

extern "C" void kernel_launch(void* const* d_in, const int* in_sizes, int n_in,
                              void* d_out, int out_size, void* d_ws, size_t ws_size,
                              hipStream_t stream) {
    const float* x    = (const float*)d_in[0];
    const float* H1w  = (const float*)d_in[1];
    const float* H1b  = (const float*)d_in[2];
    const float* H2w  = (const float*)d_in[3];
    const float* H2b  = (const float*)d_in[4];
    const float* H3w  = (const float*)d_in[5];
    const float* H3b  = (const float*)d_in[6];
    const float* outw = (const float*)d_in[7];
    const float* outb = (const float*)d_in[8];
    float* outp = (float*)d_out;
    unsigned int* ws = (unsigned int*)d_ws;

    build_tables<<<30, 256, 0, stream>>>(H1w, H1b, H2w, H2b, H3w, H3b, outw, outb, ws);

    const int B = in_sizes[0] / 256;          // 131072
    const int blocks = B / 8;                 // 16384
    modernnet_mfma<<<blocks, 256, 0, stream>>>(x, ws, outp);
}

// Round 8
// 89.660 us; speedup vs baseline: 2.0463x; 1.0332x over previous
//
#include <hip/hip_runtime.h>
#include <hip/hip_fp16.h>

typedef _Float16 f16x8 __attribute__((ext_vector_type(8)));
typedef float f32x4 __attribute__((ext_vector_type(4)));

union U4H8 { uint4 u; f16x8 h; };
__device__ inline f16x8 asH(uint4 u){ U4H8 x; x.u = u; return x.h; }
__device__ inline unsigned int pk(float a, float b){
    __half2 h = __floats2half2_rn(a, b);
    union { __half2 h; unsigned int u; } c; c.h = h; return c.u;
}
// pack two floats to f16 with relu
__device__ inline unsigned int pkr(float a, float b){
    return pk(fmaxf(a, 0.f), fmaxf(b, 0.f));
}
__device__ inline unsigned short h16(float a){
    union { __half h; unsigned short s; } c; c.h = __float2half(a); return c.s;
}

// ws dword layout: frags uint4[28][64] = dwords [0,7168);
// b1f f32[16][64] @7168 | b2f f32[4][64] @8192 | b3f f32[8][64] @8448 |
// b4f f32[4][64] @8960 ; end 9216 dwords (36 KiB).
#define NFRAG 28
#define WS_B1 7168
#define WS_B2 8192
#define WS_B3 8448
#define WS_B4 8960

// frag fi: 0-1 conv1 (k=kh*8+kw, rows=oc); 2-14 conv2 (k=tap*16+ic, rows=oc);
//          15-26 fc1 (nt*6+kk, k=pos*12+oc2, rows=fc-col); 27 fc2 (rows=logit)
__global__ __launch_bounds__(256) void build_tables(
    const float* __restrict__ H1w, const float* __restrict__ H1b,
    const float* __restrict__ H2w, const float* __restrict__ H2b,
    const float* __restrict__ H3w, const float* __restrict__ H3b,
    const float* __restrict__ outw, const float* __restrict__ outb,
    unsigned int* __restrict__ ws)
{
    const int t = threadIdx.x, b = blockIdx.x;
    float* wsf = (float*)ws;

    if (b < NFRAG) {
        if (t < 64) {
            const int lane = t, ch = lane >> 4, oc = lane & 15;
            const int fi = b;
            unsigned short us[8];
            for (int j = 0; j < 8; ++j) {
                float w = 0.f;
                if (fi < 2) {                         // conv1
                    int kh = fi * 4 + ch;
                    if (kh < 5 && j < 5 && oc < 12) w = H1w[oc * 25 + kh * 5 + j];
                } else if (fi < 15) {                 // conv2 channels-last
                    int kk = fi - 2;
                    int tap = kk * 2 + (ch >> 1);
                    int ic = (ch & 1) * 8 + j;
                    if (tap < 25 && oc < 12) {
                        int kh = tap / 5, kw = tap % 5;
                        int q = oc >> 2, icl = -1;
                        if (q == 0)      { if (ic < 8) icl = ic; }
                        else if (q == 1) { if (ic >= 4 && ic < 12) icl = ic - 4; }
                        else             { if (ic < 4) icl = ic;
                                           else if (ic >= 8 && ic < 12) icl = ic - 4; }
                        if (icl >= 0) w = H2w[((oc * 8 + icl) * 5 + kh) * 5 + kw];
                    }
                } else if (fi < 27) {                 // fc1 (k = pos*12+oc2)
                    int idx = fi - 15, nt = idx / 6, kk = idx % 6;
                    int k = kk * 32 + ch * 8 + j;     // 0..191
                    int pos = k / 12, oc2 = k % 12;
                    int col = nt * 16 + oc;
                    if (col < 30) w = H3w[(oc2 * 16 + pos) * 30 + col];
                } else {                              // fc2
                    int k = ch * 8 + j;
                    if (k < 30 && oc < 10) w = outw[k * 10 + oc];
                }
                us[j] = h16(w);
            }
            uint4 u;
            u.x = us[0] | ((unsigned int)us[1] << 16);
            u.y = us[2] | ((unsigned int)us[3] << 16);
            u.z = us[4] | ((unsigned int)us[5] << 16);
            u.w = us[6] | ((unsigned int)us[7] << 16);
            ((uint4*)ws)[fi * 64 + lane] = u;
        }
    } else if (b == NFRAG) {        // b1f: entry e=tt*4+r, lane(ch,m); oc=4ch+r
        for (int idx = t; idx < 1024; idx += 256) {
            int e = idx >> 6, l2 = idx & 63;
            int tt = e >> 2, r = e & 3;
            int oc = 4 * (l2 >> 4) + r, m2 = l2 & 15;
            int oh = 2 * tt + (m2 >> 3), ow = m2 & 7;
            float v = 0.f;
            if (oc < 12) {
                v = H1b[oc * 64 + oh * 8 + ow];
                for (int kh = 0; kh < 5; ++kh)
                    for (int kw = 0; kw < 5; ++kw) {
                        int rr = 2 * oh + kh, cc = 2 * ow + kw;
                        if (rr < 2 || rr >= 18 || cc < 2 || cc >= 18)
                            v -= H1w[oc * 25 + kh * 5 + kw];
                    }
            }
            wsf[WS_B1 + e * 64 + l2] = v;
        }
    } else {                        // b2f + b3f + b4f
        {
            int e = t >> 6, l2 = t & 63;
            int oc = 4 * (l2 >> 4) + e, m2 = l2 & 15;
            int oh = m2 >> 2, ow = m2 & 3;
            float v = 0.f;
            if (oc < 12) {
                v = H2b[oc * 16 + oh * 4 + ow];
                for (int icl = 0; icl < 8; ++icl)
                    for (int kh = 0; kh < 5; ++kh)
                        for (int kw = 0; kw < 5; ++kw) {
                            int rr = 2 * oh + kh - 2, cc = 2 * ow + kw - 2;
                            if (rr < 0 || rr >= 8 || cc < 0 || cc >= 8)
                                v -= H2w[((oc * 8 + icl) * 5 + kh) * 5 + kw];
                        }
            }
            wsf[WS_B2 + e * 64 + l2] = v;
        }
        for (int i = t; i < 512; i += 256) {    // b3f: e = nt*4+r
            int e = i >> 6, l2 = i & 63;
            int nt = e >> 2, r = e & 3, ch = l2 >> 4;
            int j = nt * 16 + 4 * ch + r;
            wsf[WS_B3 + e * 64 + l2] = (j < 30) ? H3b[j] : 0.f;
        }
        {                                        // b4f: e = r
            int e = t >> 6, l2 = t & 63, ch = l2 >> 4;
            int j = 4 * ch + e;
            wsf[WS_B4 + e * 64 + l2] = (j < 10) ? outb[j] : 0.f;
        }
    }
}

// ---------------- main kernel ----------------
// Block LDS (40448 B):
//   per-wave h1c @ wave*9216 : 2 samples x [144 pos][16 ch] half, XOR-swizzled
//     (xs overlay @ wave*9216 + s*960 : [20 rows][24 cols] half, dead after conv1)
//   shared h2 @ 36864 : 8 slots x 384 B, XOR-swizzled by slot
//   shared h3 @ 39936 : 8 slots x 64 B ([32 j] half)
#define H2B 36864
#define H3B 39936
__global__ __launch_bounds__(256, 4) void modernnet_mfma(
    const float* __restrict__ x, const unsigned int* __restrict__ ws,
    float* __restrict__ out)
{
    __shared__ uint4 lds4[2528];
    char* L = (char*)lds4;
    const int t = threadIdx.x, wave = t >> 6, l = t & 63;
    const int ch = l >> 4, m = l & 15;
    char* base = L + wave * 9216;
    const int sblk = blockIdx.x * 8;
    const int s0 = sblk + wave * 2;

    const uint4* fr = (const uint4*)ws;
    const float* wsf = (const float*)ws;

    // conv1 weight + bias frags
    uint4 c1b0 = fr[0 * 64 + l], c1b1 = fr[1 * 64 + l];
    f32x4 b1f[4];
    #pragma unroll
    for (int tt = 0; tt < 4; ++tt)
        #pragma unroll
        for (int r = 0; r < 4; ++r) b1f[tt][r] = wsf[WS_B1 + (tt * 4 + r) * 64 + l];

    // zero xs region (1920 B)
    {
        uint4 z; z.x = z.y = z.z = z.w = 0u;
        ((uint4*)base)[l] = z;
        if (l < 56) ((uint4*)base)[64 + l] = z;
    }

    // load x interior (2 samples x 16x16) -> f16
    {
        const float* xp = x + (size_t)s0 * 256 + l * 8;
        float4 v0 = *(const float4*)xp;
        float4 v1 = *(const float4*)(xp + 4);
        int sI = l >> 5, idx = l & 31;
        int r = idx >> 1, c = (idx & 1) * 8;
        char* dst = base + sI * 960 + (r + 2) * 48 + (c + 2) * 2;
        ((unsigned int*)dst)[0] = pk(v0.x, v0.y);
        ((unsigned int*)dst)[1] = pk(v0.z, v0.w);
        ((unsigned int*)dst)[2] = pk(v1.x, v1.y);
        ((unsigned int*)dst)[3] = pk(v1.z, v1.w);
    }

    // conv1: 5 reads per sample. rd[s][i] (i<4) = rows 4i+2h+ch (h=m>>3).
    // Tile tt: kh0-3 operand = rd[s][tt]; kh=4 operand = rd[s][tt+1], where
    // only ch=0 lanes carry nonzero weights (c1b1 zero for k>=8) and
    // rd[s][tt+1] ch=0 rows = 4tt+2h+4 = tile tt's kh4 rows.
    // rd[s][4] is read WAVE-UNIFORM row (no ch offset): ch>0 lanes would
    // otherwise read rows 20-21 (out of the zeroed xs region -> NaN risk).
    uint4 rd[2][5];
    #pragma unroll
    for (int s = 0; s < 2; ++s)
        #pragma unroll
        for (int i = 0; i < 5; ++i) {
            const int cho = (i < 4) ? ch * 48 : 0;
            const unsigned int* p = (const unsigned int*)
                (base + s * 960 + (2 * i + (m >> 3)) * 96 + (m & 7) * 4 + cho);
            rd[s][i] = make_uint4(p[0], p[1], p[2], p[3]);
        }
    f32x4 acc1[8];
    #pragma unroll
    for (int i = 0; i < 8; ++i) {
        const int s = i >> 2, tt = i & 3;
        f32x4 acc = b1f[tt];
        acc = __builtin_amdgcn_mfma_f32_16x16x32_f16(asH(c1b0), asH(rd[s][tt]), acc, 0, 0, 0);
        acc = __builtin_amdgcn_mfma_f32_16x16x32_f16(asH(c1b1), asH(rd[s][tt + 1]), acc, 0, 0, 0);
        acc1[i] = acc;
    }

    // conv1 epilogue: rows=oc in regs, col=pos -> b64 writes into swizzled h1c
    #pragma unroll
    for (int i = 0; i < 8; ++i) {
        const int s = i >> 2, tt = i & 3;
        const int pos = (2 * tt + (m >> 3) + 2) * 12 + (m & 7) + 2;
        const int off = ((pos << 5) + ch * 8) ^ ((pos & 12) << 2);
        unsigned int w0 = pkr(acc1[i][0], acc1[i][1]);
        unsigned int w1 = pkr(acc1[i][2], acc1[i][3]);
        *(uint2*)(base + s * 4608 + off) = make_uint2(w0, w1);
    }

    // conv2 per-lane read offsets — compile-time tap table, no divides
    int c2off[13];
    {
        const int mb = 24 * (m >> 2) + 2 * (m & 3);
        const int hb = (ch & 1) << 4;
        const int sel = (ch >> 1) & 1;
        #pragma unroll
        for (int kk = 0; kk < 13; ++kk) {
            const int t0 = 2 * kk;
            const int t1 = (2 * kk + 1 <= 24) ? 2 * kk + 1 : 24;
            const int p0 = (t0 / 5) * 12 + (t0 % 5);
            const int p1 = (t1 / 5) * 12 + (t1 % 5);
            int pos = mb + (sel ? p1 : p0);
            c2off[kk] = ((pos << 5) + hb) ^ ((pos & 12) << 2);
        }
    }

    // prefetch conv2 weights + bias
    uint4 c2b[13];
    #pragma unroll
    for (int kk = 0; kk < 13; ++kk) c2b[kk] = fr[(2 + kk) * 64 + l];
    f32x4 b2f;
    #pragma unroll
    for (int r = 0; r < 4; ++r) b2f[r] = wsf[WS_B2 + r * 64 + l];

    // zero h1c pad rings
    {
        uint4 z; z.x = z.y = z.z = z.w = 0u;
        #pragma unroll
        for (int k2 = 0; k2 < 5; ++k2) {
            int idx = l + k2 * 64;
            int smp = (idx >= 160) ? 1 : 0;
            int ci = idx - smp * 160;
            int pi = ci >> 1, half = ci & 1;
            int pos;
            if (pi < 24) pos = pi;
            else if (pi < 48) pos = pi + 96;
            else {
                int q = pi - 48;
                int c = q & 3; c = (c < 2) ? c : c + 8;
                pos = (2 + (q >> 2)) * 12 + c;
            }
            int off = ((pos << 5) + (half << 4)) ^ ((pos & 12) << 2);
            *(uint4*)(base + smp * 4608 + off) = z;
        }
    }

    // conv2: two independent acc chains; h2 writes XOR-swizzled by slot
    {
        const char* h0 = base;
        const char* h1 = base + 4608;
        f32x4 a0 = b2f, a1 = b2f;
        #pragma unroll
        for (int kk = 0; kk < 13; ++kk) {
            uint4 r0 = *(const uint4*)(h0 + c2off[kk]);
            uint4 r1 = *(const uint4*)(h1 + c2off[kk]);
            a0 = __builtin_amdgcn_mfma_f32_16x16x32_f16(asH(c2b[kk]), asH(r0), a0, 0, 0, 0);
            a1 = __builtin_amdgcn_mfma_f32_16x16x32_f16(asH(c2b[kk]), asH(r1), a1, 0, 0, 0);
        }
        if (ch < 3) {
            const int sl0 = wave * 2, sl1 = wave * 2 + 1;
            const int off = m * 24 + ch * 8;
            unsigned int w0 = pkr(a0[0], a0[1]);
            unsigned int w1 = pkr(a0[2], a0[3]);
            *(uint2*)(L + H2B + sl0 * 384 + (off ^ (sl0 << 4))) = make_uint2(w0, w1);
            w0 = pkr(a1[0], a1[1]);
            w1 = pkr(a1[2], a1[3]);
            *(uint2*)(L + H2B + sl1 * 384 + (off ^ (sl1 << 4))) = make_uint2(w0, w1);
        }
    }

    // prefetch fc1 frags (waves 0,1 only; nt = wave)
    uint4 afc[6];
    if (wave < 2) {
        #pragma unroll
        for (int kk = 0; kk < 6; ++kk) afc[kk] = fr[(15 + wave * 6 + kk) * 64 + l];
    }

    __syncthreads();

    // fc1: rows = fc cols (regs), cols = 8 samples (slot = m&7, swizzled read)
    if (wave < 2) {
        const int nt = wave;
        const int slot = m & 7;
        f32x4 acc;
        #pragma unroll
        for (int r = 0; r < 4; ++r) acc[r] = wsf[WS_B3 + (nt * 4 + r) * 64 + l];
        #pragma unroll
        for (int kk = 0; kk < 6; ++kk) {
            uint4 bb = *(const uint4*)(L + H2B + slot * 384 +
                                       ((kk * 64 + ch * 16) ^ (slot << 4)));
            acc = __builtin_amdgcn_mfma_f32_16x16x32_f16(asH(afc[kk]), asH(bb), acc, 0, 0, 0);
        }
        if (m < 8) {
            unsigned int w0 = pkr(acc[0], acc[1]);
            unsigned int w1 = pkr(acc[2], acc[3]);
            *(uint2*)(L + H3B + m * 64 + nt * 32 + ch * 8) = make_uint2(w0, w1);
        }
    }

    __syncthreads();

    // fc2: wave 0 only, 1 MFMA for all 8 samples
    if (wave == 0) {
        uint4 aw = fr[27 * 64 + l];
        uint4 bb = *(const uint4*)(L + H3B + (m & 7) * 64 + ch * 16);
        f32x4 acc;
        #pragma unroll
        for (int r = 0; r < 4; ++r) acc[r] = wsf[WS_B4 + r * 64 + l];
        acc = __builtin_amdgcn_mfma_f32_16x16x32_f16(asH(aw), asH(bb), acc, 0, 0, 0);
        if (m < 8) {
            float* op = out + (size_t)(sblk + m) * 10 + 4 * ch;
            if (ch < 2) {
                *(float2*)op       = make_float2(acc[0], acc[1]);
                *(float2*)(op + 2) = make_float2(acc[2], acc[3]);
            } else if (ch == 2) {
                *(float2*)op       = make_float2(acc[0], acc[1]);
            }
        }
    }
}

extern "C" void kernel_launch(void* const* d_in, const int* in_sizes, int n_in,
                              void* d_out, int out_size, void* d_ws, size_t ws_size,
                              hipStream_t stream) {
    const float* x    = (const float*)d_in[0];
    const float* H1w  = (const float*)d_in[1];
    const float* H1b  = (const float*)d_in[2];
    const float* H2w  = (const float*)d_in[3];
    const float* H2b  = (const float*)d_in[4];
    const float* H3w  = (const float*)d_in[5];
    const float* H3b  = (const float*)d_in[6];
    const float* outw = (const float*)d_in[7];
    const float* outb = (const float*)d_in[8];
    float* outp = (float*)d_out;
    unsigned int* ws = (unsigned int*)d_ws;

    build_tables<<<30, 256, 0, stream>>>(H1w, H1b, H2w, H2b, H3w, H3b, outw, outb, ws);

    const int B = in_sizes[0] / 256;          // 131072
    const int blocks = B / 8;                 // 16384
    modernnet_mfma<<<blocks, 256, 0, stream>>>(x, ws, outp);
}